// Round 1
// baseline (627.613 us; speedup 1.0000x reference)
//
#include <hip/hip_runtime.h>
#include <hip/hip_bf16.h>
#include <hip/hip_fp16.h>

typedef _Float16 f16;
typedef _Float16 f16x8 __attribute__((ext_vector_type(8)));
typedef _Float16 f16x4 __attribute__((ext_vector_type(4)));
typedef float f32x4 __attribute__((ext_vector_type(4)));

#define N_OBJ 8192
#define HIDDEN 512
#define POOL 4096
#define N_REL 32768
#define N_RELCLS 51
#define NUM_OBJ_CLS 151

// ---------------- workspace layout (bytes, 256-aligned) ----------------
// E16     : 8192*512*2          = 8,388,608    @ 0
// Wpe16   : 512*1024*2          = 1,048,576    @ 8,388,608
// WcatT16 : 4096*1024*2         = 8,388,608    @ 9,437,184
// F_T     : 2*4096*512*2        = 8,388,608    @ 17,825,792
// P       : 2*8192*4096*2       = 134,217,728  @ 26,214,400
// bias    : 4096*4              = 16,384       @ 160,432,128
// preds   : 8192*4              = 32,768       @ 160,448,512
// wfrag   : 128*4*64*8*2        = 524,288      @ 160,481,280
#define WS_E16    0UL
#define WS_WPE16  8388608UL
#define WS_WCATT  9437184UL
#define WS_FT     17825792UL
#define WS_P      26214400UL
#define WS_BIAS   160432128UL
#define WS_PREDS  160448512UL
#define WS_WFRAG  160481280UL

// ---------------- fp32 -> fp16 convert (vectorized x4) ----------------
__global__ void k_convert(const float* __restrict__ in, f16* __restrict__ out, int n4) {
    int i = blockIdx.x * blockDim.x + threadIdx.x;
    if (i < n4) {
        f32x4 v = ((const f32x4*)in)[i];
        f16x4 h;
        h[0] = (f16)v[0]; h[1] = (f16)v[1]; h[2] = (f16)v[2]; h[3] = (f16)v[3];
        ((f16x4*)out)[i] = h;
    }
}

// ---------------- transpose + convert: in (R x C f32) -> out (C x R f16) ----------------
__global__ void k_transpose_cvt(const float* __restrict__ in, f16* __restrict__ out, int R, int C) {
    __shared__ float tile[32][33];
    int c0 = blockIdx.x * 32, r0 = blockIdx.y * 32;
    int tx = threadIdx.x, ty = threadIdx.y;   // block (32,8)
    #pragma unroll
    for (int i = 0; i < 4; i++)
        tile[ty + 8 * i][tx] = in[(size_t)(r0 + ty + 8 * i) * C + c0 + tx];
    __syncthreads();
    #pragma unroll
    for (int i = 0; i < 4; i++)
        out[(size_t)(c0 + ty + 8 * i) * R + r0 + tx] = (f16)tile[tx][ty + 8 * i];
}

// ---------------- combined bias: bias[c] = sum_j b_pe[j]*Wcat[j,c] + b_cat[c] ----------------
__global__ void k_bias(const float* __restrict__ b_pe, const float* __restrict__ Wcat,
                       const float* __restrict__ b_cat, float* __restrict__ bias) {
    int c = blockIdx.x * 256 + threadIdx.x;
    float acc = b_cat[c];
    for (int j = 0; j < 2 * HIDDEN; j++)
        acc += b_pe[j] * Wcat[(size_t)j * POOL + c];
    bias[c] = acc;
}

// ---------------- argmax of E @ W_obj + b_obj, f64 accumulation ----------------
#define OPB 8
__global__ __launch_bounds__(192) void k_argmax(const float* __restrict__ E, const float* __restrict__ Wobj,
                                                const float* __restrict__ bobj, int* __restrict__ preds) {
    __shared__ float se[OPB][HIDDEN];
    __shared__ double sv[OPB][NUM_OBJ_CLS];
    int o0 = blockIdx.x * OPB;
    for (int i = threadIdx.x; i < OPB * HIDDEN; i += 192)
        se[i / HIDDEN][i % HIDDEN] = E[(size_t)o0 * HIDDEN + i];
    __syncthreads();
    int j = threadIdx.x;
    if (j < NUM_OBJ_CLS) {
        double acc[OPB];
        double b = (double)bobj[j];
        #pragma unroll
        for (int o = 0; o < OPB; o++) acc[o] = b;
        for (int k = 0; k < HIDDEN; k++) {
            double w = (double)Wobj[(size_t)k * NUM_OBJ_CLS + j];
            #pragma unroll
            for (int o = 0; o < OPB; o++) acc[o] += (double)se[o][k] * w;
        }
        #pragma unroll
        for (int o = 0; o < OPB; o++) sv[o][j] = acc[o];
    }
    __syncthreads();
    if (threadIdx.x < OPB) {
        int o = threadIdx.x;
        double best = sv[o][0]; int bi = 0;
        for (int jj = 1; jj < NUM_OBJ_CLS; jj++) {
            double v = sv[o][jj];
            if (v > best) { best = v; bi = jj; }
        }
        preds[o0 + o] = bi;
    }
}

// ---------------- pack W_rel into MFMA B-fragment layout ----------------
// frag[(kstep*4 + nt)*64 + lane] (f16x8); value = W_rel[k, n], n = nt*16 + (lane&15),
// k = kstep*32 + (lane>>4)*8 + j ; zero-pad n >= 51
__global__ void k_wrel_frag(const float* __restrict__ Wrel, f16* __restrict__ frag) {
    int lane = threadIdx.x & 63;
    int nt = threadIdx.x >> 6;
    int kstep = blockIdx.x;
    int n = nt * 16 + (lane & 15);
    int k0 = kstep * 32 + (lane >> 4) * 8;
    f16x8 v;
    #pragma unroll
    for (int jj = 0; jj < 8; jj++) {
        float w = (n < N_RELCLS) ? Wrel[(size_t)(k0 + jj) * N_RELCLS + n] : 0.0f;
        v[jj] = (f16)w;
    }
    ((f16x8*)frag)[(size_t)(kstep * 4 + nt) * 64 + lane] = v;
}

// ---------------- generic "NT" fp16 GEMM ----------------
// C[n][m] = sum_k A[m][k] * B[n][k] (+ bias[m]); A: MxK (lda), B: NxK (ldb), C: NxM (ldc), f16 out
// 128x128 block tile, 4 waves each 64x64, direct-global fragment loads (no LDS).
// MFMA 16x16x32 f16 layouts: A-frag lane: row=l&15, k=(l>>4)*8+j ; B-frag same with n=l&15;
// C/D: col=lane&15, row=(lane>>4)*4+reg  [per guide §3, dtype-independent]
__global__ __launch_bounds__(256) void k_gemm_nt(const f16* __restrict__ A, const f16* __restrict__ B,
                                                 f16* __restrict__ C, const float* __restrict__ bias,
                                                 int K, int lda, int ldb, int ldc) {
    int lane = threadIdx.x & 63;
    int w = threadIdx.x >> 6;
    int wm = w >> 1, wn = w & 1;
    int m0 = blockIdx.y * 128 + wm * 64;
    int n0 = blockIdx.x * 128 + wn * 64;
    int lr = lane & 15, lg = lane >> 4;
    f32x4 acc[4][4] = {};
    const f16* Ap = A + (size_t)(m0 + lr) * lda + lg * 8;
    const f16* Bp = B + (size_t)(n0 + lr) * ldb + lg * 8;
    for (int k0 = 0; k0 < K; k0 += 32) {
        f16x8 a[4], b[4];
        #pragma unroll
        for (int i = 0; i < 4; i++) a[i] = *(const f16x8*)(Ap + (size_t)i * 16 * lda + k0);
        #pragma unroll
        for (int jj = 0; jj < 4; jj++) b[jj] = *(const f16x8*)(Bp + (size_t)jj * 16 * ldb + k0);
        #pragma unroll
        for (int i = 0; i < 4; i++)
            #pragma unroll
            for (int jj = 0; jj < 4; jj++)
                acc[i][jj] = __builtin_amdgcn_mfma_f32_16x16x32_f16(a[i], b[jj], acc[i][jj], 0, 0, 0);
    }
    #pragma unroll
    for (int i = 0; i < 4; i++) {
        int mb = m0 + i * 16 + lg * 4;
        f32x4 bi = {};
        if (bias) bi = *(const f32x4*)(bias + mb);
        #pragma unroll
        for (int jj = 0; jj < 4; jj++) {
            int n = n0 + jj * 16 + lr;
            f16x4 hv;
            #pragma unroll
            for (int r = 0; r < 4; r++) hv[r] = (f16)(acc[i][jj][r] + bi[r]);
            *(f16x4*)(C + (size_t)n * ldc + mb) = hv;
        }
    }
}

// ---------------- final fused kernel ----------------
// out[r, 0:51] = ((P_h[h[r]] + P_t[t[r]]) * U[r]) @ Wrel + b_rel + freq_bias[lbl(r)]
// 4 waves/block, each wave: 16 rows x 64 cols, K=4096. A-fragments built in registers.
__global__ __launch_bounds__(256) void k_final(const f16* __restrict__ P, const float* __restrict__ U,
                                               const int* __restrict__ relp, const int* __restrict__ preds,
                                               const f16* __restrict__ wfrag, const float* __restrict__ brel,
                                               const float* __restrict__ fbias, float* __restrict__ out) {
    int w = threadIdx.x >> 6;
    int lane = threadIdx.x & 63;
    int lr = lane & 15, lg = lane >> 4;
    int r0 = blockIdx.x * 64 + w * 16;
    int arow = r0 + lr;                       // row this lane supplies A-fragments for
    int h = relp[2 * arow], t = relp[2 * arow + 1];
    const f16* ph = P + (size_t)h * POOL;
    const f16* pt = P + (size_t)(N_OBJ + t) * POOL;
    const float* u = U + (size_t)arow * POOL;
    f32x4 acc[4] = {};
    for (int ks = 0; ks < POOL / 32; ks++) {
        int ka = ks * 32 + lg * 8;
        f16x8 vh = *(const f16x8*)(ph + ka);
        f16x8 vt = *(const f16x8*)(pt + ka);
        f32x4 u0 = *(const f32x4*)(u + ka);
        f32x4 u1 = *(const f32x4*)(u + ka + 4);
        f16x8 a;
        #pragma unroll
        for (int jj = 0; jj < 8; jj++) {
            float uu = (jj < 4) ? u0[jj] : u1[jj - 4];
            a[jj] = (f16)(((float)vh[jj] + (float)vt[jj]) * uu);
        }
        const f16x8* bf = (const f16x8*)wfrag + (size_t)ks * 4 * 64 + lane;
        #pragma unroll
        for (int nt = 0; nt < 4; nt++)
            acc[nt] = __builtin_amdgcn_mfma_f32_16x16x32_f16(a, bf[nt * 64], acc[nt], 0, 0, 0);
    }
    #pragma unroll
    for (int r = 0; r < 4; r++) {
        int row = r0 + lg * 4 + r;            // C-layout row for this lane/reg
        int h2 = relp[2 * row], t2 = relp[2 * row + 1];
        int lbl = preds[h2] * NUM_OBJ_CLS + preds[t2];
        const float* fb = fbias + (size_t)lbl * N_RELCLS;
        #pragma unroll
        for (int nt = 0; nt < 4; nt++) {
            int j = nt * 16 + lr;             // C-layout col
            if (j < N_RELCLS)
                out[(size_t)row * N_RELCLS + j] = acc[nt][r] + brel[j] + fb[j];
        }
    }
}

extern "C" void kernel_launch(void* const* d_in, const int* in_sizes, int n_in,
                              void* d_out, int out_size, void* d_ws, size_t ws_size,
                              hipStream_t stream) {
    const float* edge_ctx = (const float*)d_in[0];
    const int*   relp     = (const int*)d_in[1];
    const float* U        = (const float*)d_in[2];
    const float* Wobj     = (const float*)d_in[3];
    const float* bobj     = (const float*)d_in[4];
    const float* Wpe      = (const float*)d_in[5];
    const float* bpe      = (const float*)d_in[6];
    const float* Wcat     = (const float*)d_in[7];
    const float* bcat     = (const float*)d_in[8];
    const float* Wrel     = (const float*)d_in[9];
    const float* brel     = (const float*)d_in[10];
    const float* fbias    = (const float*)d_in[11];
    float* out = (float*)d_out;

    char* ws = (char*)d_ws;
    f16*   E16    = (f16*)(ws + WS_E16);
    f16*   Wpe16  = (f16*)(ws + WS_WPE16);
    f16*   WcatT  = (f16*)(ws + WS_WCATT);
    f16*   FT     = (f16*)(ws + WS_FT);
    f16*   P      = (f16*)(ws + WS_P);
    float* bias   = (float*)(ws + WS_BIAS);
    int*   preds  = (int*)(ws + WS_PREDS);
    f16*   wfrag  = (f16*)(ws + WS_WFRAG);

    // 1. converts
    k_convert<<<4096, 256, 0, stream>>>(edge_ctx, E16, N_OBJ * HIDDEN / 4);
    k_convert<<<512, 256, 0, stream>>>(Wpe, Wpe16, HIDDEN * 2 * HIDDEN / 4);
    // 2. Wcat transpose+convert: (1024 x 4096 f32) -> (4096 x 1024 f16)
    k_transpose_cvt<<<dim3(POOL / 32, (2 * HIDDEN) / 32), dim3(32, 8), 0, stream>>>(Wcat, WcatT, 2 * HIDDEN, POOL);
    // 3. combined bias
    k_bias<<<POOL / 256, 256, 0, stream>>>(bpe, Wcat, bcat, bias);
    // 4. object class argmax (f64 accum)
    k_argmax<<<N_OBJ / OPB, 192, 0, stream>>>(edge_ctx, Wobj, bobj, preds);
    // 5. W_rel fragment packing
    k_wrel_frag<<<POOL / 32, 256, 0, stream>>>(Wrel, wfrag);
    // 6. fold: F_T[part][c][k] = sum_j Wpe[k, part*512+j] * Wcat[part*512+j, c]
    //    M=512 (k), N=4096 (c), K=512 (j)
    k_gemm_nt<<<dim3(POOL / 128, HIDDEN / 128), 256, 0, stream>>>(
        Wpe16, WcatT, FT, nullptr, HIDDEN, 2 * HIDDEN, 2 * HIDDEN, HIDDEN);
    k_gemm_nt<<<dim3(POOL / 128, HIDDEN / 128), 256, 0, stream>>>(
        Wpe16 + HIDDEN, WcatT + HIDDEN, FT + (size_t)POOL * HIDDEN, nullptr, HIDDEN, 2 * HIDDEN, 2 * HIDDEN, HIDDEN);
    // 7. proj: P[part][o][c] = sum_k F_T[part][c][k] * E16[o][k]  (+bias[c] on head part)
    //    M=4096 (c), N=8192 (o), K=512
    k_gemm_nt<<<dim3(N_OBJ / 128, POOL / 128), 256, 0, stream>>>(
        FT, E16, P, bias, HIDDEN, HIDDEN, HIDDEN, POOL);
    k_gemm_nt<<<dim3(N_OBJ / 128, POOL / 128), 256, 0, stream>>>(
        FT + (size_t)POOL * HIDDEN, E16, P + (size_t)N_OBJ * POOL, nullptr, HIDDEN, HIDDEN, HIDDEN, POOL);
    // 8. final fused gather + union-mult + GEMM4 + freq_bias
    k_final<<<N_REL / 64, 256, 0, stream>>>(P, U, relp, preds, wfrag, brel, fbias, out);
}

// Round 2
// 405.849 us; speedup vs baseline: 1.5464x; 1.5464x over previous
//
#include <hip/hip_runtime.h>
#include <hip/hip_bf16.h>
#include <hip/hip_fp16.h>

typedef _Float16 f16;
typedef _Float16 f16x8 __attribute__((ext_vector_type(8)));
typedef _Float16 f16x4 __attribute__((ext_vector_type(4)));
typedef float f32x4 __attribute__((ext_vector_type(4)));

#define N_OBJ 8192
#define HIDDEN 512
#define POOL 4096
#define N_REL 32768
#define N_RELCLS 51
#define NUM_OBJ_CLS 151

// ---------------- workspace layout (bytes, 256-aligned) ----------------
#define WS_E16    0UL
#define WS_WPE16  8388608UL
#define WS_WCATT  9437184UL
#define WS_FT     17825792UL
#define WS_P      26214400UL
#define WS_BIAS   160432128UL
#define WS_PREDS  160448512UL
#define WS_WFRAG  160481280UL

// ---------------- async global->LDS 16B ----------------
typedef const __attribute__((address_space(1))) void* gas_ptr;
typedef __attribute__((address_space(3))) void* las_ptr;
__device__ __forceinline__ void gl_lds16(const f16* g, f16* l) {
    __builtin_amdgcn_global_load_lds((gas_ptr)g, (las_ptr)l, 16, 0, 0);
}

// ---------------- fp32 -> fp16 convert (vectorized x4) ----------------
__global__ void k_convert(const float* __restrict__ in, f16* __restrict__ out, int n4) {
    int i = blockIdx.x * blockDim.x + threadIdx.x;
    if (i < n4) {
        f32x4 v = ((const f32x4*)in)[i];
        f16x4 h;
        h[0] = (f16)v[0]; h[1] = (f16)v[1]; h[2] = (f16)v[2]; h[3] = (f16)v[3];
        ((f16x4*)out)[i] = h;
    }
}

// ---------------- transpose + convert: in (R x C f32) -> out (C x R f16) ----------------
__global__ void k_transpose_cvt(const float* __restrict__ in, f16* __restrict__ out, int R, int C) {
    __shared__ float tile[32][33];
    int c0 = blockIdx.x * 32, r0 = blockIdx.y * 32;
    int tx = threadIdx.x, ty = threadIdx.y;   // block (32,8)
    #pragma unroll
    for (int i = 0; i < 4; i++)
        tile[ty + 8 * i][tx] = in[(size_t)(r0 + ty + 8 * i) * C + c0 + tx];
    __syncthreads();
    #pragma unroll
    for (int i = 0; i < 4; i++)
        out[(size_t)(c0 + ty + 8 * i) * R + r0 + tx] = (f16)tile[tx][ty + 8 * i];
}

// ---------------- combined bias: bias[c] = sum_j b_pe[j]*Wcat[j,c] + b_cat[c] ----------------
// 128 blocks x 256 threads; 32 cols/block, 8-way j-split + LDS reduce.
__global__ __launch_bounds__(256) void k_bias(const float* __restrict__ b_pe, const float* __restrict__ Wcat,
                                              const float* __restrict__ b_cat, float* __restrict__ bias) {
    __shared__ float red[8][32];
    int c = blockIdx.x * 32 + (threadIdx.x & 31);
    int jq = threadIdx.x >> 5;
    float acc = 0.0f;
    #pragma unroll 4
    for (int j = jq * 128; j < jq * 128 + 128; j++)
        acc += b_pe[j] * Wcat[(size_t)j * POOL + c];
    red[jq][threadIdx.x & 31] = acc;
    __syncthreads();
    if (jq == 0) {
        float s = b_cat[c];
        #pragma unroll
        for (int q = 0; q < 8; q++) s += red[q][threadIdx.x & 31];
        bias[c] = s;
    }
}

// ---------------- argmax of E @ W_obj + b_obj, f64 accumulation ----------------
#define OPB 8
__global__ __launch_bounds__(192) void k_argmax(const float* __restrict__ E, const float* __restrict__ Wobj,
                                                const float* __restrict__ bobj, int* __restrict__ preds) {
    __shared__ float se[OPB][HIDDEN];
    __shared__ double sv[OPB][NUM_OBJ_CLS];
    int o0 = blockIdx.x * OPB;
    for (int i = threadIdx.x; i < OPB * HIDDEN; i += 192)
        se[i / HIDDEN][i % HIDDEN] = E[(size_t)o0 * HIDDEN + i];
    __syncthreads();
    int j = threadIdx.x;
    if (j < NUM_OBJ_CLS) {
        double acc[OPB];
        double b = (double)bobj[j];
        #pragma unroll
        for (int o = 0; o < OPB; o++) acc[o] = b;
        for (int k = 0; k < HIDDEN; k++) {
            double w = (double)Wobj[(size_t)k * NUM_OBJ_CLS + j];
            #pragma unroll
            for (int o = 0; o < OPB; o++) acc[o] += (double)se[o][k] * w;
        }
        #pragma unroll
        for (int o = 0; o < OPB; o++) sv[o][j] = acc[o];
    }
    __syncthreads();
    if (threadIdx.x < OPB) {
        int o = threadIdx.x;
        double best = sv[o][0]; int bi = 0;
        for (int jj = 1; jj < NUM_OBJ_CLS; jj++) {
            double v = sv[o][jj];
            if (v > best) { best = v; bi = jj; }
        }
        preds[o0 + o] = bi;
    }
}

// ---------------- pack W_rel into MFMA B-fragment layout ----------------
__global__ void k_wrel_frag(const float* __restrict__ Wrel, f16* __restrict__ frag) {
    int lane = threadIdx.x & 63;
    int nt = threadIdx.x >> 6;
    int kstep = blockIdx.x;
    int n = nt * 16 + (lane & 15);
    int k0 = kstep * 32 + (lane >> 4) * 8;
    f16x8 v;
    #pragma unroll
    for (int jj = 0; jj < 8; jj++) {
        float w = (n < N_RELCLS) ? Wrel[(size_t)(k0 + jj) * N_RELCLS + n] : 0.0f;
        v[jj] = (f16)w;
    }
    ((f16x8*)frag)[(size_t)(kstep * 4 + nt) * 64 + lane] = v;
}

// ---------------- LDS-staged fp16 NT GEMM, m97 structure ----------------
// C[n][m] = sum_k A[m][k]*B[n][k] (+bias[m] if m<biasLimit)
// 128x128 tile, BK=64, 4 waves (2x2 of 64x64), global_load_lds w=16,
// XOR swizzle koff ^= (row&7)<<4 (pre-swizzled source + swizzled ds_read).
// SPLITM: store C[n][m] into P[part=m/4096][n][m%4096] (proj path).
template<bool SPLITM>
__global__ __launch_bounds__(256) void k_gemm(const f16* __restrict__ A, const f16* __restrict__ B,
                                              f16* __restrict__ C, const float* __restrict__ bias,
                                              int K, int lda, int ldb, int ldc,
                                              long aZ, long bZ, long cZ, int biasLimit) {
    __shared__ f16 As[128 * 64];
    __shared__ f16 Bs[128 * 64];
    long z = blockIdx.z;
    A += z * aZ; B += z * bZ; C += z * cZ;

    int tid = threadIdx.x;
    int w = tid >> 6, lane = tid & 63;
    int wm = w >> 1, wn = w & 1;
    int lr = lane & 15, lg = lane >> 4;
    int mBase = blockIdx.y * 128;
    int nBase = blockIdx.x * 128;

    // staging descriptors: 1024 chunks of 16B per tile, 4 per thread
    const f16* aSrc[4]; const f16* bSrc[4];
    f16* aDst[4]; f16* bDst[4];
    #pragma unroll
    for (int p = 0; p < 4; p++) {
        int c = p * 256 + tid;
        int row = c >> 3, slot = c & 7;
        int scol = (slot ^ (row & 7)) * 8;   // inverse-swizzled global source
        aSrc[p] = A + (size_t)(mBase + row) * lda + scol;
        bSrc[p] = B + (size_t)(nBase + row) * ldb + scol;
        aDst[p] = As + p * 2048 + w * 512;   // wave-uniform, linear LDS dest
        bDst[p] = Bs + p * 2048 + w * 512;
    }

    int swz = (lr & 7) << 4;                 // per-lane read swizzle (bytes)
    f32x4 acc[4][4] = {};

    for (int k0 = 0; k0 < K; k0 += 64) {
        if (k0) __syncthreads();
        #pragma unroll
        for (int p = 0; p < 4; p++) {
            gl_lds16(aSrc[p] + k0, aDst[p]);
            gl_lds16(bSrc[p] + k0, bDst[p]);
        }
        __syncthreads();
        #pragma unroll
        for (int kh = 0; kh < 2; kh++) {
            f16x8 av[4], bv[4];
            int koff = ((kh * 64 + lg * 16) ^ swz) >> 1;   // f16 elems within row
            #pragma unroll
            for (int i = 0; i < 4; i++) {
                av[i] = *(const f16x8*)(As + (wm * 64 + i * 16 + lr) * 64 + koff);
                bv[i] = *(const f16x8*)(Bs + (wn * 64 + i * 16 + lr) * 64 + koff);
            }
            #pragma unroll
            for (int i = 0; i < 4; i++)
                #pragma unroll
                for (int jj = 0; jj < 4; jj++)
                    acc[i][jj] = __builtin_amdgcn_mfma_f32_16x16x32_f16(av[i], bv[jj], acc[i][jj], 0, 0, 0);
        }
    }

    #pragma unroll
    for (int i = 0; i < 4; i++) {
        int mb = mBase + wm * 64 + i * 16 + lg * 4;
        f32x4 bi = {};
        if (bias && mb < biasLimit) bi = *(const f32x4*)(bias + mb);
        #pragma unroll
        for (int jj = 0; jj < 4; jj++) {
            int n = nBase + wn * 64 + jj * 16 + lr;
            f16x4 hv;
            #pragma unroll
            for (int r = 0; r < 4; r++) hv[r] = (f16)(acc[i][jj][r] + bi[r]);
            if (SPLITM) {
                size_t off = ((size_t)((mb >= POOL) ? N_OBJ : 0) + n) * POOL + (mb & (POOL - 1));
                *(f16x4*)(C + off) = hv;
            } else {
                *(f16x4*)(C + (size_t)n * ldc + mb) = hv;
            }
        }
    }
}

// ---------------- final fused kernel ----------------
// out[r, 0:51] = ((P_h[h[r]] + P_t[t[r]]) * U[r]) @ Wrel + b_rel + freq_bias[lbl(r)]
__global__ __launch_bounds__(256) void k_final(const f16* __restrict__ P, const float* __restrict__ U,
                                               const int* __restrict__ relp, const int* __restrict__ preds,
                                               const f16* __restrict__ wfrag, const float* __restrict__ brel,
                                               const float* __restrict__ fbias, float* __restrict__ out) {
    int w = threadIdx.x >> 6;
    int lane = threadIdx.x & 63;
    int lr = lane & 15, lg = lane >> 4;
    int r0 = blockIdx.x * 64 + w * 16;
    int arow = r0 + lr;                       // row this lane supplies A-fragments for
    int h = relp[2 * arow], t = relp[2 * arow + 1];
    const f16* ph = P + (size_t)h * POOL;
    const f16* pt = P + (size_t)(N_OBJ + t) * POOL;
    const float* u = U + (size_t)arow * POOL;
    f32x4 acc[4] = {};
    for (int ks = 0; ks < POOL / 32; ks++) {
        int ka = ks * 32 + lg * 8;
        f16x8 vh = *(const f16x8*)(ph + ka);
        f16x8 vt = *(const f16x8*)(pt + ka);
        f32x4 u0 = __builtin_nontemporal_load((const f32x4*)(u + ka));
        f32x4 u1 = __builtin_nontemporal_load((const f32x4*)(u + ka + 4));
        f16x8 a;
        #pragma unroll
        for (int jj = 0; jj < 8; jj++) {
            float uu = (jj < 4) ? u0[jj] : u1[jj - 4];
            a[jj] = (f16)(((float)vh[jj] + (float)vt[jj]) * uu);
        }
        const f16x8* bf = (const f16x8*)wfrag + (size_t)ks * 4 * 64 + lane;
        #pragma unroll
        for (int nt = 0; nt < 4; nt++)
            acc[nt] = __builtin_amdgcn_mfma_f32_16x16x32_f16(a, bf[nt * 64], acc[nt], 0, 0, 0);
    }
    #pragma unroll
    for (int r = 0; r < 4; r++) {
        int row = r0 + lg * 4 + r;            // C-layout row for this lane/reg
        int h2 = relp[2 * row], t2 = relp[2 * row + 1];
        int lbl = preds[h2] * NUM_OBJ_CLS + preds[t2];
        const float* fb = fbias + (size_t)lbl * N_RELCLS;
        #pragma unroll
        for (int nt = 0; nt < 4; nt++) {
            int j = nt * 16 + lr;             // C-layout col
            if (j < N_RELCLS)
                out[(size_t)row * N_RELCLS + j] = acc[nt][r] + brel[j] + fb[j];
        }
    }
}

extern "C" void kernel_launch(void* const* d_in, const int* in_sizes, int n_in,
                              void* d_out, int out_size, void* d_ws, size_t ws_size,
                              hipStream_t stream) {
    const float* edge_ctx = (const float*)d_in[0];
    const int*   relp     = (const int*)d_in[1];
    const float* U        = (const float*)d_in[2];
    const float* Wobj     = (const float*)d_in[3];
    const float* bobj     = (const float*)d_in[4];
    const float* Wpe      = (const float*)d_in[5];
    const float* bpe      = (const float*)d_in[6];
    const float* Wcat     = (const float*)d_in[7];
    const float* bcat     = (const float*)d_in[8];
    const float* Wrel     = (const float*)d_in[9];
    const float* brel     = (const float*)d_in[10];
    const float* fbias    = (const float*)d_in[11];
    float* out = (float*)d_out;

    char* ws = (char*)d_ws;
    f16*   E16    = (f16*)(ws + WS_E16);
    f16*   Wpe16  = (f16*)(ws + WS_WPE16);
    f16*   WcatT  = (f16*)(ws + WS_WCATT);
    f16*   FT     = (f16*)(ws + WS_FT);
    f16*   P      = (f16*)(ws + WS_P);
    float* bias   = (float*)(ws + WS_BIAS);
    int*   preds  = (int*)(ws + WS_PREDS);
    f16*   wfrag  = (f16*)(ws + WS_WFRAG);

    // 1. converts
    k_convert<<<4096, 256, 0, stream>>>(edge_ctx, E16, N_OBJ * HIDDEN / 4);
    k_convert<<<512, 256, 0, stream>>>(Wpe, Wpe16, HIDDEN * 2 * HIDDEN / 4);
    // 2. Wcat transpose+convert: (1024 x 4096 f32) -> (4096 x 1024 f16)
    k_transpose_cvt<<<dim3(POOL / 32, (2 * HIDDEN) / 32), dim3(32, 8), 0, stream>>>(Wcat, WcatT, 2 * HIDDEN, POOL);
    // 3. combined bias
    k_bias<<<POOL / 32, 256, 0, stream>>>(bpe, Wcat, bcat, bias);
    // 4. object class argmax (f64 accum)
    k_argmax<<<N_OBJ / OPB, 192, 0, stream>>>(edge_ctx, Wobj, bobj, preds);
    // 5. W_rel fragment packing
    k_wrel_frag<<<POOL / 32, 256, 0, stream>>>(Wrel, wfrag);
    // 6. fold (both parts in one dispatch, grid.z=2):
    //    FT[z][c][k] = sum_j Wpe16[k, z*512+j] * WcatT[c, z*512+j]
    k_gemm<false><<<dim3(POOL / 128, HIDDEN / 128, 2), 256, 0, stream>>>(
        Wpe16, WcatT, FT, nullptr, HIDDEN, 2 * HIDDEN, 2 * HIDDEN, HIDDEN,
        512L, 512L, (long)POOL * HIDDEN, 0);
    // 7. fused proj (M=8192 covers both parts): P[part][o][c] = FT[part][c] . E16[o] (+bias on part 0)
    k_gemm<true><<<dim3(N_OBJ / 128, (2 * POOL) / 128, 1), 256, 0, stream>>>(
        FT, E16, P, bias, HIDDEN, HIDDEN, HIDDEN, POOL,
        0L, 0L, 0L, POOL);
    // 8. final fused gather + union-mult + GEMM4 + freq_bias
    k_final<<<N_REL / 64, 256, 0, stream>>>(P, U, relp, preds, wfrag, brel, fbias, out);
}